// Round 2
// baseline (112.039 us; speedup 1.0000x reference)
//
#include <hip/hip_runtime.h>
#include <math.h>

#define R_DIM 5
#define A_DIM 8
#define K0    8
#define KK    7

__global__ __launch_bounds__(256) void bc_kernel(
    const float* __restrict__ tmpl,
    const float* __restrict__ proj,
    float* __restrict__ out,
    int ntask)
{
#pragma clang fp contract(off)
    int tid = blockIdx.x * blockDim.x + threadIdx.x;
    if (tid >= ntask) return;
    int v  = tid / (R_DIM * A_DIM);
    int ra = tid - v * (R_DIM * A_DIM);

    // template point (r,a)
    float tx = tmpl[ra * 2 + 0];
    float ty = tmpl[ra * 2 + 1];

    // load the 8 projection points for this v; squared norms; distances
    float px[K0], py[K0], ps[K0], pd[K0];
    const float* pv = proj + (size_t)v * (K0 * 2);
#pragma unroll
    for (int k = 0; k < K0; ++k) {
        float x = pv[2 * k + 0];
        float y = pv[2 * k + 1];
        px[k] = x; py[k] = y;
        ps[k] = x * x + y * y;                  // s_all (same values as reference)
        float dx = tx - x, dy = ty - y;
        pd[k] = sqrtf(dx * dx + dy * dy);       // jnp.linalg.norm, no fma (contract off)
    }

    // stable ascending argsort via ranks: rank[k] = #{l : d[l]<d[k] or (==, l<k)}
    int rank[K0];
#pragma unroll
    for (int k = 0; k < K0; ++k) {
        int r = 0;
#pragma unroll
        for (int l = 0; l < K0; ++l) {
            if (pd[l] < pd[k] || (pd[l] == pd[k] && l < k)) r++;
        }
        rank[k] = r;
    }

    // gather sorted points via compile-time-indexed selects (keep in VGPRs)
    float sx[K0], sy[K0], ss[K0];
    int   sidx[K0];
#pragma unroll
    for (int pos = 0; pos < K0; ++pos) {
        float x = 0.f, y = 0.f, s = 0.f; int id = 0;
#pragma unroll
        for (int k = 0; k < K0; ++k) {
            bool hit = (rank[k] == pos);
            x  = hit ? px[k] : x;
            y  = hit ? py[k] : y;
            s  = hit ? ps[k] : s;
            id = hit ? k    : id;
        }
        sx[pos] = x; sy[pos] = y; ss[pos] = s; sidx[pos] = id;
    }

    float cx = sx[0], cy = sy[0], scs = ss[0];

    // "others" = sorted[1..7]; edge vectors and dot products
    float ox[KK], oy[KK], osq[KK];
    float v0x[KK], v0y[KK], d00[KK], d02[KK];
    float v2x = tx - cx, v2y = ty - cy;
#pragma unroll
    for (int n = 0; n < KK; ++n) {
        ox[n] = sx[n + 1]; oy[n] = sy[n + 1]; osq[n] = ss[n + 1];
        v0x[n] = ox[n] - cx;
        v0y[n] = oy[n] - cy;
        d00[n] = v0x[n] * v0x[n] + v0y[n] * v0y[n];
        d02[n] = v0x[n] * v2x + v0y[n] * v2y;
    }

    // scan all (n,m) pairs in row-major order; strict < argmin (first occurrence)
    float bestScore = __builtin_inff();
    int   bestIdx = 0;
    float bw0 = 0.f, bw1 = 0.f, bw2 = 0.f;

#pragma unroll
    for (int n = 0; n < KK; ++n) {
#pragma unroll
        for (int m = 0; m < KK; ++m) {
            if (n == m) continue;   // eye -> weights inf -> score inf (never selected)
            float d01   = v0x[n] * v0x[m] + v0y[n] * v0y[m];
            float denom = d00[n] * d00[m] - d01 * d01;
            float inv   = 1.0f / denom;
            float w2 = (d00[m] * d02[n] - d01 * d02[m]) * inv;
            float w1 = (d00[n] * d02[m] - d01 * d02[n]) * inv;
            float w0 = (1.0f - w2) - w1;
            // invalid = (w<=0) | isnan(w)  ->  valid = all strictly > 0 (NaN fails)
            bool valid = (w0 > 0.0f) && (w1 > 0.0f) && (w2 > 0.0f);
            if (!valid) continue;

            // Delaunay-style test: all j (j!=n, j!=m) must have det <= 0
            bool ok = true;
#pragma unroll
            for (int j = 0; j < KK; ++j) {
                if (j == n || j == m) continue;
                float ax = cx - ox[j], ay = cy - oy[j], as_ = scs - osq[j];
                float bx = ox[n] - ox[j], by = oy[n] - oy[j], bs = osq[n] - osq[j];
                float dx = ox[m] - ox[j], dy = oy[m] - oy[j], ds = osq[m] - osq[j];
                float det = ax * (by * ds - bs * dy)
                          - ay * (bx * ds - bs * dx)
                          + as_ * (bx * dy - by * dx);
                ok = ok && (det <= 0.0f);
            }
            if (!ok) continue;

            float w0s = w0 * w0, w2s = w2 * w2, w1s = w1 * w1;
            float sc = fmaxf(fmaxf(w0s, w2s), w1s);
            if (sc < bestScore) {
                bestScore = sc;
                bestIdx = n * KK + m;
                bw0 = w0; bw1 = w1; bw2 = w2;
            }
        }
    }

    // outputs: weights stacked [w0, w2, w1]; zeroed if no valid triangle
    int row = bestIdx / KK;
    int col = bestIdx - row * KK;
    int i1 = 0, i2 = 0;
#pragma unroll
    for (int n = 0; n < KK; ++n) {
        if (row == n) i1 = sidx[n + 1];
        if (col == n) i2 = sidx[n + 1];
    }

    size_t ob = (size_t)tid * 3;
    out[ob + 0] = bw0;
    out[ob + 1] = bw2;
    out[ob + 2] = bw1;

    size_t off = (size_t)ntask * 3;
    out[off + ob + 0] = (float)sidx[0];
    out[off + ob + 1] = (float)i1;
    out[off + ob + 2] = (float)i2;
}

extern "C" void kernel_launch(void* const* d_in, const int* in_sizes, int n_in,
                              void* d_out, int out_size, void* d_ws, size_t ws_size,
                              hipStream_t stream) {
    const float* tmpl = (const float*)d_in[0];   // (5, 8, 2) float32
    const float* proj = (const float*)d_in[1];   // (5000, 8, 2) float32
    float* out = (float*)d_out;                  // [V*R*A*3 weights][V*R*A*3 indices]

    int V = in_sizes[1] / (K0 * 2);
    int ntask = V * R_DIM * A_DIM;
    int threads = 256;
    int blocks = (ntask + threads - 1) / threads;
    bc_kernel<<<blocks, threads, 0, stream>>>(tmpl, proj, out, ntask);
}

// Round 3
// 81.172 us; speedup vs baseline: 1.3803x; 1.3803x over previous
//
#include <hip/hip_runtime.h>
#include <math.h>

#define R_DIM 5
#define A_DIM 8
#define K0    8
#define KK    7
#define NPAIR 21

// pair id for p<q in 0..6  (row-packed upper triangle)
#define PID(p, q) ((p) * 7 - (p) * ((p) + 1) / 2 + ((q) - (p) - 1))

__global__ __launch_bounds__(256) void bc_kernel(
    const float* __restrict__ tmpl,
    const float* __restrict__ proj,
    float* __restrict__ out,
    int ntask)
{
#pragma clang fp contract(off)
    const float INF = __builtin_inff();
    int tid = blockIdx.x * blockDim.x + threadIdx.x;
    if (tid >= ntask) return;
    int v  = tid / (R_DIM * A_DIM);
    int ra = tid - v * (R_DIM * A_DIM);

    float tx = tmpl[ra * 2 + 0];
    float ty = tmpl[ra * 2 + 1];

    // ---- load 8 projection points (vectorized), squared norms, distances ----
    const float4* pv4 = reinterpret_cast<const float4*>(proj + (size_t)v * (K0 * 2));
    float4 q0 = pv4[0], q1 = pv4[1], q2 = pv4[2], q3 = pv4[3];
    float px[K0] = {q0.x, q0.z, q1.x, q1.z, q2.x, q2.z, q3.x, q3.z};
    float py[K0] = {q0.y, q0.w, q1.y, q1.w, q2.y, q2.w, q3.y, q3.w};
    float ps[K0], pd[K0];
#pragma unroll
    for (int k = 0; k < K0; ++k) {
        ps[k] = px[k] * px[k] + py[k] * py[k];
        float dx = tx - px[k], dy = ty - py[k];
        pd[k] = sqrtf(dx * dx + dy * dy);
    }

    // ---- stable ranks (ascending distance, ties by index) ----
    int rank[K0];
#pragma unroll
    for (int k = 0; k < K0; ++k) {
        int r = 0;
#pragma unroll
        for (int l = 0; l < K0; ++l)
            r += (pd[l] < pd[k] || (pd[l] == pd[k] && l < k)) ? 1 : 0;
        rank[k] = r;
    }

    // ---- closest point ----
    float cx = 0.f, cy = 0.f, cs = 0.f; int cidx = 0;
#pragma unroll
    for (int k = 0; k < K0; ++k) {
        bool h = (rank[k] == 0);
        cx = h ? px[k] : cx;  cy = h ? py[k] : cy;
        cs = h ? ps[k] : cs;  cidx = h ? k : cidx;
    }

    // ---- compress the 7 "others" (original order preserved) ----
    float ox[KK], oy[KK], osq[KK]; int ork[KK], oid[KK];
#pragma unroll
    for (int n = 0; n < KK; ++n) {
        bool ge = (n >= cidx);
        ox[n]  = ge ? px[n + 1]   : px[n];
        oy[n]  = ge ? py[n + 1]   : py[n];
        osq[n] = ge ? ps[n + 1]   : ps[n];
        ork[n] = ge ? rank[n + 1] : rank[n];   // 1..7, all distinct
        oid[n] = ge ? (n + 1)     : n;
    }

    // ---- edge vectors / dot products ----
    float v2x = tx - cx, v2y = ty - cy;
    float vx[KK], vy[KK], d00[KK], d02[KK];
#pragma unroll
    for (int n = 0; n < KK; ++n) {
        vx[n] = ox[n] - cx;
        vy[n] = oy[n] - cy;
        d00[n] = vx[n] * vx[n] + vy[n] * vy[n];
        d02[n] = vx[n] * v2x + vy[n] * v2y;
    }

    // ---- in-circle determinants: per origin k, all pairs p<q (p,q != k) ----
    // det(p,q | origin k) matches ref det(n=p, m=q, j=k) bitwise; det(q,p|k) = -det exactly.
    float dmn[NPAIR], dmx[NPAIR];
#pragma unroll
    for (int i = 0; i < NPAIR; ++i) { dmn[i] = INF; dmx[i] = -INF; }

#pragma unroll
    for (int k = 0; k < KK; ++k) {
        float akx = cx - ox[k], aky = cy - oy[k], aks = cs - osq[k];
        float ex[KK], ey[KK], es[KK];
#pragma unroll
        for (int i = 0; i < KK; ++i) {
            if (i == k) continue;               // compile-time pruned
            ex[i] = ox[i] - ox[k];
            ey[i] = oy[i] - oy[k];
            es[i] = osq[i] - osq[k];
        }
#pragma unroll
        for (int p = 0; p < KK - 1; ++p) {
#pragma unroll
            for (int q = p + 1; q < KK; ++q) {
                if (p == k || q == k) continue; // compile-time pruned
                const int pid = PID(p, q);
                float m1 = ey[p] * es[q] - es[p] * ey[q];
                float m2 = ex[p] * es[q] - es[p] * ex[q];
                float m3 = ex[p] * ey[q] - ey[p] * ex[q];
                float det = (akx * m1 - aky * m2) + aks * m3;  // ref op order
                dmn[pid] = fminf(dmn[pid], det);
                dmx[pid] = fmaxf(dmx[pid], det);
            }
        }
    }

    // ---- scan 21 unordered pairs; each gives 2 oriented candidates ----
    // argmin tie-break == reference row-major order via (score, rankPairCode) lex compare
    float bsc = INF; int brij = 0x7fffffff;
    float bw0 = 0.f, bw1 = 0.f, bw2 = 0.f;
    int bi = 0, bj = 0;

#pragma unroll
    for (int p = 0; p < KK - 1; ++p) {
#pragma unroll
        for (int q = p + 1; q < KK; ++q) {
            const int pid = PID(p, q);
            float d01 = vx[p] * vx[q] + vy[p] * vy[q];
            float den = d00[p] * d00[q] - d01 * d01;
            float inv = 1.0f / den;
            float u = (d00[q] * d02[p] - d01 * d02[q]) * inv;  // w2 of (p,q) == w1 of (q,p)
            float w = (d00[p] * d02[q] - d01 * d02[p]) * inv;  // w1 of (p,q) == w2 of (q,p)
            float w0a = (1.0f - u) - w;                        // w0 of (p,q), ref order
            float w0b = (1.0f - w) - u;                        // w0 of (q,p), ref order
            bool posuw = (u > 0.0f) && (w > 0.0f);
            bool okA = (dmx[pid] <= 0.0f);                     // all det(p,q,*) <= 0
            bool okB = (dmn[pid] >= 0.0f);                     // all det(q,p,*) <= 0 (exact neg)
            float muw = fmaxf(u * u, w * w);
            float scA = fmaxf(w0a * w0a, muw);
            float scB = fmaxf(w0b * w0b, muw);
            int rpq = ork[p] * 8 + ork[q];
            int rqp = ork[q] * 8 + ork[p];

            bool vA = okA && posuw && (w0a > 0.0f) && (scA < INF);
            bool tA = vA && (scA < bsc || (scA == bsc && rpq < brij));
            bsc = tA ? scA : bsc;  brij = tA ? rpq : brij;
            bw0 = tA ? w0a : bw0;  bw2 = tA ? u : bw2;  bw1 = tA ? w : bw1;
            bi  = tA ? oid[p] : bi;  bj = tA ? oid[q] : bj;

            bool vB = okB && posuw && (w0b > 0.0f) && (scB < INF);
            bool tB = vB && (scB < bsc || (scB == bsc && rqp < brij));
            bsc = tB ? scB : bsc;  brij = tB ? rqp : brij;
            bw0 = tB ? w0b : bw0;  bw2 = tB ? w : bw2;  bw1 = tB ? u : bw1;
            bi  = tB ? oid[q] : bi;  bj = tB ? oid[p] : bj;
        }
    }

    // ---- fallback (all scores inf): ref argmin -> flat 0 -> diagonal (0,0) ----
    int sec = 0;
#pragma unroll
    for (int n = 0; n < KK; ++n) sec = (ork[n] == 1) ? oid[n] : sec;
    bool found = (bsc < INF);
    float o0 = found ? bw0 : 0.0f;
    float o1 = found ? bw2 : 0.0f;
    float o2 = found ? bw1 : 0.0f;
    int j1 = found ? bi : sec;
    int j2 = found ? bj : sec;

    size_t ob = (size_t)tid * 3;
    out[ob + 0] = o0;
    out[ob + 1] = o1;
    out[ob + 2] = o2;
    size_t off = (size_t)ntask * 3;
    out[off + ob + 0] = (float)cidx;
    out[off + ob + 1] = (float)j1;
    out[off + ob + 2] = (float)j2;
}

extern "C" void kernel_launch(void* const* d_in, const int* in_sizes, int n_in,
                              void* d_out, int out_size, void* d_ws, size_t ws_size,
                              hipStream_t stream) {
    const float* tmpl = (const float*)d_in[0];   // (5, 8, 2) float32
    const float* proj = (const float*)d_in[1];   // (5000, 8, 2) float32
    float* out = (float*)d_out;                  // [V*R*A*3 weights][V*R*A*3 indices]

    int V = in_sizes[1] / (K0 * 2);
    int ntask = V * R_DIM * A_DIM;
    int threads = 256;
    int blocks = (ntask + threads - 1) / threads;
    bc_kernel<<<blocks, threads, 0, stream>>>(tmpl, proj, out, ntask);
}